// Round 8
// baseline (221.936 us; speedup 1.0000x reference)
//
#include <hip/hip_runtime.h>
#include <hip/hip_fp16.h>

// DiffusionConv: out = x@Tf0 + Px@(Tb0+Tb1) + P2x@(Tf1+Tb2) + P3x@Tf2
// R8: cnt padded to ONE 64B line per row (cnt[r<<4]) -- R4..R7 showed bin
// time invariant to writeback bytes (72->48MB, 53->50us), so the suspected
// limiter is same-line atomic serialization (was 256 atomics/line, now 16).
// Rest identical to R7 (fp16 features, 4B packed bucket entries).

#define N_NODES 50000
#define N_EDGES 800000
#define C 64
#define CAP 64  // bucket capacity; rows ~ Poisson(16), P(>64) ~ 2e-18

// x (fp32) -> x_h (fp16), 4 elems/thread
__global__ __launch_bounds__(256) void xhalf_kernel(
        const float* __restrict__ x, __half* __restrict__ xh) {
    int i = blockIdx.x * blockDim.x + threadIdx.x;
    if (i >= N_NODES * C / 4) return;
    float4 v = ((const float4*)x)[i];
    union { float2 f2; __half2 h2[2]; } u;
    u.h2[0] = __floats2half2_rn(v.x, v.y);
    u.h2[1] = __floats2half2_rn(v.z, v.w);
    ((float2*)xh)[i] = u.f2;
}

// one atomic pass: cnt[r*16]++ (one line per row) and drop packed entry
__global__ __launch_bounds__(256) void bin_kernel(
        const int* __restrict__ row, const int* __restrict__ col,
        const float* __restrict__ w, int* __restrict__ cnt,
        unsigned int* __restrict__ bkt) {
    int e = blockIdx.x * blockDim.x + threadIdx.x;
    if (e >= N_EDGES) return;
    int r = row[e];
    unsigned int c = (unsigned int)col[e];
    unsigned short wh = __half_as_ushort(__float2half_rn(w[e]));
    int p = atomicAdd(&cnt[r << 4], 1);   // padded: one 64B line per row
    if (p < CAP) {
        bkt[(r << 6) + p] = (c << 16) | (unsigned int)wh;
    }
}

// 16 lanes per node: deg = sum w over bucket, dinv = rsqrt(deg)
__global__ __launch_bounds__(256) void dinv_kernel(
        const int* __restrict__ cnt, const unsigned int* __restrict__ bkt,
        float* __restrict__ dinv) {
    int g = (blockIdx.x * blockDim.x + threadIdx.x) >> 4;
    int l = threadIdx.x & 15;
    if (g >= N_NODES) return;
    int m = min(cnt[g << 4], CAP);
    int s = g << 6;
    float sum = 0.f;
    for (int j = l; j < m; j += 16)
        sum += __half2float(__ushort_as_half((unsigned short)(bkt[s + j] & 0xFFFFu)));
#pragma unroll
    for (int o = 8; o; o >>= 1) sum += __shfl_down(sum, o, 16);
    if (l == 0) dinv[g] = (sum > 0.f) ? rsqrtf(sum) : 0.f;
}

// 4 nodes per wave: quarter-wave q owns node wave*4+q; lane ql (0-15) holds
// channels 4ql..4ql+3. Gathers are 8B (half4). dinv[col] gathered per edge;
// dinv[row] at epilogue.
__global__ __launch_bounds__(256) void prop_kernel(
        const __half* __restrict__ xin, __half* __restrict__ xout,
        const int* __restrict__ cnt, const unsigned int* __restrict__ bkt,
        const float* __restrict__ dinv) {
    int wave = (blockIdx.x * blockDim.x + threadIdx.x) >> 6;
    int lane = threadIdx.x & 63;
    int q = lane >> 4;
    int ql = lane & 15;
    int node = (wave << 2) + q;     // 12500 waves * 4 = 50000 exactly
    if (node >= N_NODES) return;
    int m = min(cnt[node << 4], CAP);
    int base = node << 6;
    float ax = 0.f, ay = 0.f, az = 0.f, aw = 0.f;
    for (int cb = 0; cb < m; cb += 16) {
        int cj = 0;
        float nj = 0.f;
        int idx = cb + ql;
        if (idx < m) {
            unsigned int b = bkt[base + idx];
            int c = (int)(b >> 16);
            cj = c << 6;                                   // half-element row offset
            nj = __half2float(__ushort_as_half((unsigned short)(b & 0xFFFFu))) * dinv[c];
        }
        int rem = m - cb;
        if (rem > 16) rem = 16;
        int mm = (rem + 7) & ~7;    // padded lanes carry cj=0,nj=0
        for (int jo = 0; jo < mm; jo += 8) {
            int cs[8];
            float ns[8];
            float2 vs[8];
#pragma unroll
            for (int t = 0; t < 8; ++t) {
                cs[t] = __shfl(cj, (q << 4) + jo + t);
                ns[t] = __shfl(nj, (q << 4) + jo + t);
            }
#pragma unroll
            for (int t = 0; t < 8; ++t)
                vs[t] = *(const float2*)(xin + cs[t] + (ql << 2));
#pragma unroll
            for (int t = 0; t < 8; ++t) {
                const __half2* hp = (const __half2*)&vs[t];
                float2 a = __half22float2(hp[0]);
                float2 b = __half22float2(hp[1]);
                ax += ns[t] * a.x;
                ay += ns[t] * a.y;
                az += ns[t] * b.x;
                aw += ns[t] * b.y;
            }
        }
    }
    float dr = dinv[node];
    union { float2 f2; __half2 h2[2]; } u;
    u.h2[0] = __floats2half2_rn(dr * ax, dr * ay);
    u.h2[1] = __floats2half2_rn(dr * az, dr * aw);
    *(float2*)(xout + base + (ql << 2)) = u.f2;
}

// combined weights Wc[j][ci][co], j in {x, Px, P2x, P3x}
__global__ void combine_w_kernel(const float* __restrict__ tf, const float* __restrict__ tb,
                                 float* __restrict__ wc) {
    int idx = blockIdx.x * blockDim.x + threadIdx.x;
    if (idx >= 4 * 64 * 64) return;
    int j = idx >> 12;
    int rem = idx & 4095;  // ci*64 + co
    float v;
    if (j == 0)      v = tf[rem];                         // Tf0
    else if (j == 1) v = tb[rem] + tb[4096 + rem];        // Tb0 + Tb1
    else if (j == 2) v = tf[4096 + rem] + tb[8192 + rem]; // Tf1 + Tb2
    else             v = tf[8192 + rem];                  // Tf2
    wc[idx] = v;
}

// out_tile (+)= Xa_tile @ wcp[0] + Xb_tile @ wcp[1]; Xa/Xb half -> fp32 LDS
__global__ __launch_bounds__(256) void gemm2_kernel(
        const __half* __restrict__ xa, const __half* __restrict__ xb,
        const float* __restrict__ wcp, float* __restrict__ out, int accum) {
    __shared__ float XsT[64][68];
    __shared__ float Ws[64][64];
    const int tid = threadIdx.x;
    const int tx = tid & 15;
    const int ty = tid >> 4;
    const int nb = blockIdx.x << 6;
    const __half* srcs[2] = {xa, xb};
    float acc[4][4];
#pragma unroll
    for (int i = 0; i < 4; ++i)
#pragma unroll
        for (int j = 0; j < 4; ++j) acc[i][j] = 0.f;

    for (int j = 0; j < 2; ++j) {
        const __half* src = srcs[j];
        const float4* wsrc = (const float4*)(wcp + (j << 12));
#pragma unroll
        for (int it = 0; it < 4; ++it) {
            int f = tid + (it << 8);
            int r = f >> 4;
            int c4 = f & 15;
            float4 wv = wsrc[f];
            *(float4*)&Ws[r][c4 << 2] = wv;
            int n = nb + r;
            float2 a = make_float2(0.f, 0.f), b = make_float2(0.f, 0.f);
            if (n < N_NODES) {
                float2 raw = *(const float2*)(src + ((size_t)n << 6) + (c4 << 2));
                const __half2* hp = (const __half2*)&raw;
                a = __half22float2(hp[0]);
                b = __half22float2(hp[1]);
            }
            XsT[(c4 << 2) + 0][r] = a.x;
            XsT[(c4 << 2) + 1][r] = a.y;
            XsT[(c4 << 2) + 2][r] = b.x;
            XsT[(c4 << 2) + 3][r] = b.y;
        }
        __syncthreads();
#pragma unroll 8
        for (int k = 0; k < 64; ++k) {
            float4 bv = *(const float4*)&Ws[k][tx << 2];
            float4 av = *(const float4*)&XsT[k][ty << 2];
            acc[0][0] += av.x * bv.x; acc[0][1] += av.x * bv.y;
            acc[0][2] += av.x * bv.z; acc[0][3] += av.x * bv.w;
            acc[1][0] += av.y * bv.x; acc[1][1] += av.y * bv.y;
            acc[1][2] += av.y * bv.z; acc[1][3] += av.y * bv.w;
            acc[2][0] += av.z * bv.x; acc[2][1] += av.z * bv.y;
            acc[2][2] += av.z * bv.z; acc[2][3] += av.z * bv.w;
            acc[3][0] += av.w * bv.x; acc[3][1] += av.w * bv.y;
            acc[3][2] += av.w * bv.z; acc[3][3] += av.w * bv.w;
        }
        __syncthreads();
    }
#pragma unroll
    for (int i = 0; i < 4; ++i) {
        int n = nb + (ty << 2) + i;
        if (n < N_NODES) {
            float* dst = out + ((size_t)n << 6) + (tx << 2);
            float4 v = make_float4(acc[i][0], acc[i][1], acc[i][2], acc[i][3]);
            if (accum) {
                float4 o = *(const float4*)dst;
                v.x += o.x; v.y += o.y; v.z += o.z; v.w += o.w;
            }
            *(float4*)dst = v;
        }
    }
}

extern "C" void kernel_launch(void* const* d_in, const int* in_sizes, int n_in,
                              void* d_out, int out_size, void* d_ws, size_t ws_size,
                              hipStream_t stream) {
    const float* x  = (const float*)d_in[0];
    const int*   ei = (const int*)d_in[1];   // row = ei[0..E), col = ei[E..2E)
    const float* ew = (const float*)d_in[2];
    const float* tf = (const float*)d_in[3];
    const float* tb = (const float*)d_in[4];
    float* out = (float*)d_out;

    const int* row = ei;
    const int* col = ei + N_EDGES;

    // workspace layout (4B words), total ~36 MB
    float* ws = (float*)d_ws;
    size_t off = 0;
    int*    cnt  = (int*)(ws + off); off += (size_t)N_NODES * 16;  // 1 line/row
    float*  dinv = ws + off; off += 50048;
    unsigned int* bkt = (unsigned int*)(ws + off); off += (size_t)N_NODES * CAP;
    __half* xh   = (__half*)(ws + off); off += (size_t)N_NODES * C / 2;
    __half* tA   = (__half*)(ws + off); off += (size_t)N_NODES * C / 2;
    __half* tB   = (__half*)(ws + off); off += (size_t)N_NODES * C / 2;
    float*  wc   = ws + off; off += 4 * 64 * 64;

    hipMemsetAsync(cnt, 0, (size_t)N_NODES * 16 * sizeof(int), stream);

    xhalf_kernel<<<(N_NODES * C / 4 + 255) / 256, 256, 0, stream>>>(x, xh);

    const int EB = (N_EDGES + 255) / 256;
    bin_kernel<<<EB, 256, 0, stream>>>(row, col, ew, cnt, bkt);

    dinv_kernel<<<(N_NODES * 16 + 255) / 256, 256, 0, stream>>>(cnt, bkt, dinv);

    const int PB = (N_NODES + 15) / 16;   // 4 nodes/wave, 4 waves/block
    prop_kernel<<<PB, 256, 0, stream>>>(xh, tA, cnt, bkt, dinv);   // tx1
    prop_kernel<<<PB, 256, 0, stream>>>(tA, tB, cnt, bkt, dinv);   // tx2

    combine_w_kernel<<<(4 * 64 * 64 + 255) / 256, 256, 0, stream>>>(tf, tb, wc);

    const int GB = (N_NODES + 63) / 64;
    // out = x@W0 + tx1@W1  (then tA is free)
    gemm2_kernel<<<GB, 256, 0, stream>>>(xh, tA, wc, out, 0);

    prop_kernel<<<PB, 256, 0, stream>>>(tB, tA, cnt, bkt, dinv);   // tx3

    // out += tx2@W2 + tx3@W3
    gemm2_kernel<<<GB, 256, 0, stream>>>(tB, tA, wc + 2 * 4096, out, 1);
}

// Round 9
// 216.527 us; speedup vs baseline: 1.0250x; 1.0250x over previous
//
#include <hip/hip_runtime.h>
#include <hip/hip_fp16.h>

// DiffusionConv: out = x@Tf0 + Px@(Tb0+Tb1) + P2x@(Tf1+Tb2) + P3x@Tf2
// R9: partition-sorted binning. R4-R8 proved the single-pass scatter is
// pinned at ~50us by random 64B-sector writebacks (WRITE ~= E*64B always).
// Now: hist -> scan -> partition-scatter (merged-line writes) -> per-partition
// LDS binning (LDS atomics, contiguous 64KB dumps, dinv fused).
// fp16 features, 4B packed bucket entries (col<<16|half(w)). One 4-term GEMM.

#define N_NODES 50000
#define N_EDGES 800000
#define C 64
#define CAP 64          // bucket capacity; rows ~ Poisson(16), P(>64) ~ 2e-18
#define NPART 196       // partitions of 256 rows: p = r >> 8
#define EPB 8192        // edges per block in hist/scatter
#define NEB 98          // ceil(800000/8192)
#define XH_BLOCKS 782   // ceil(800000 float4 chunks / 1024)

// A: blocks 0..NEB-1: partition histogram; blocks NEB..: x fp32->fp16
__global__ __launch_bounds__(1024) void hist_kernel(
        const int* __restrict__ row, int* __restrict__ cntmat,
        const float* __restrict__ x, __half* __restrict__ xh) {
    const int tid = threadIdx.x;
    if (blockIdx.x >= NEB) {
        int i = (blockIdx.x - NEB) * 1024 + tid;
        if (i < N_NODES * C / 4) {
            float4 v = ((const float4*)x)[i];
            union { float2 f2; __half2 h2[2]; } u;
            u.h2[0] = __floats2half2_rn(v.x, v.y);
            u.h2[1] = __floats2half2_rn(v.z, v.w);
            ((float2*)xh)[i] = u.f2;
        }
        return;
    }
    __shared__ int h[NPART];
    if (tid < NPART) h[tid] = 0;
    __syncthreads();
    int base = blockIdx.x * EPB;
#pragma unroll
    for (int i = 0; i < 8; ++i) {
        int e = base + i * 1024 + tid;
        if (e < N_EDGES) atomicAdd(&h[row[e] >> 8], 1);
    }
    __syncthreads();
    if (tid < NPART) cntmat[tid * NEB + blockIdx.x] = h[tid];
}

// B: one block scans cntmat[NPART*NEB] (partition-major) -> exclusive offmat
__global__ __launch_bounds__(1024) void scan_kernel(
        const int* __restrict__ cntmat, int* __restrict__ offmat) {
    __shared__ int s[1024];
    const int t = threadIdx.x;
    const int NTOT = NPART * NEB;          // 19208
    const int CH = (NTOT + 1023) / 1024;   // 19
    int s0 = t * CH;
    int s1 = min(NTOT, s0 + CH);
    int local = 0;
    for (int i = s0; i < s1; ++i) local += cntmat[i];
    s[t] = local;
    __syncthreads();
    for (int ofs = 1; ofs < 1024; ofs <<= 1) {
        int v = (t >= ofs) ? s[t - ofs] : 0;
        __syncthreads();
        s[t] += v;
        __syncthreads();
    }
    int run = s[t] - local;   // exclusive
    for (int i = s0; i < s1; ++i) {
        offmat[i] = run;
        run += cntmat[i];
    }
}

// C: partition-sorted scatter. Block b claims LDS cursors from offmat[.][b],
// writes uint2{col<<16|half(w), r&255} runs per partition (merged lines).
__global__ __launch_bounds__(1024) void scatter_kernel(
        const int* __restrict__ row, const int* __restrict__ col,
        const float* __restrict__ w, const int* __restrict__ offmat,
        uint2* __restrict__ pedges) {
    __shared__ int cur[NPART];
    const int tid = threadIdx.x;
    if (tid < NPART) cur[tid] = offmat[tid * NEB + blockIdx.x];
    __syncthreads();
    int base = blockIdx.x * EPB;
#pragma unroll
    for (int i = 0; i < 8; ++i) {
        int e = base + i * 1024 + tid;
        if (e < N_EDGES) {
            int r = row[e];
            unsigned int c = (unsigned int)col[e];
            unsigned int wh = (unsigned int)__half_as_ushort(__float2half_rn(w[e]));
            int slot = atomicAdd(&cur[r >> 8], 1);
            pedges[slot] = make_uint2((c << 16) | wh, (unsigned int)(r & 255));
        }
    }
}

// D: one block per partition: LDS-bin 256 rows x 64 slots, fuse dinv,
// dump buckets contiguously.
__global__ __launch_bounds__(1024) void build_kernel(
        const uint2* __restrict__ pedges, const int* __restrict__ offmat,
        unsigned int* __restrict__ bkt, int* __restrict__ cnt,
        float* __restrict__ dinv) {
    __shared__ unsigned int lbuck[256 * CAP];   // 64 KB
    __shared__ int lcnt[256];
    const int tid = threadIdx.x;
    const int p = blockIdx.x;
    if (tid < 256) lcnt[tid] = 0;
    __syncthreads();
    int s = offmat[p * NEB];
    int e = (p == NPART - 1) ? N_EDGES : offmat[(p + 1) * NEB];
    for (int i = s + tid; i < e; i += 1024) {
        uint2 en = pedges[i];
        int rl = (int)en.y;
        int slot = atomicAdd(&lcnt[rl], 1);
        if (slot < CAP) lbuck[(rl << 6) + slot] = en.x;
    }
    __syncthreads();
    if (tid < 256) {
        int m = min(lcnt[tid], CAP);
        int g = (p << 8) + tid;
        float sum = 0.f;
        for (int j = 0; j < m; ++j)
            sum += __half2float(__ushort_as_half(
                (unsigned short)(lbuck[(tid << 6) + j] & 0xFFFFu)));
        if (g < N_NODES) {
            cnt[g] = m;
            dinv[g] = (sum > 0.f) ? rsqrtf(sum) : 0.f;
        }
    }
    __syncthreads();
    // contiguous 64 KB dump (uint4-vectorized)
    const uint4* src = (const uint4*)lbuck;
    uint4* dst = (uint4*)(bkt + ((size_t)p << 14));
    for (int i = tid; i < 256 * CAP / 4; i += 1024) dst[i] = src[i];
}

// 4 nodes per wave: quarter-wave q owns node wave*4+q; lane ql (0-15) holds
// channels 4ql..4ql+3. 8B gathers; dinv[col] per edge; dinv[row] at epilogue.
__global__ __launch_bounds__(256) void prop_kernel(
        const __half* __restrict__ xin, __half* __restrict__ xout,
        const int* __restrict__ cnt, const unsigned int* __restrict__ bkt,
        const float* __restrict__ dinv) {
    int wave = (blockIdx.x * blockDim.x + threadIdx.x) >> 6;
    int lane = threadIdx.x & 63;
    int q = lane >> 4;
    int ql = lane & 15;
    int node = (wave << 2) + q;     // 12500 waves * 4 = 50000 exactly
    if (node >= N_NODES) return;
    int m = min(cnt[node], CAP);
    int base = node << 6;
    float ax = 0.f, ay = 0.f, az = 0.f, aw = 0.f;
    for (int cb = 0; cb < m; cb += 16) {
        int cj = 0;
        float nj = 0.f;
        int idx = cb + ql;
        if (idx < m) {
            unsigned int b = bkt[base + idx];
            int c = (int)(b >> 16);
            cj = c << 6;                                   // half-elem row offset
            nj = __half2float(__ushort_as_half((unsigned short)(b & 0xFFFFu))) * dinv[c];
        }
        int rem = m - cb;
        if (rem > 16) rem = 16;
        int mm = (rem + 7) & ~7;    // padded lanes carry cj=0,nj=0
        for (int jo = 0; jo < mm; jo += 8) {
            int cs[8];
            float ns[8];
            float2 vs[8];
#pragma unroll
            for (int t = 0; t < 8; ++t) {
                cs[t] = __shfl(cj, (q << 4) + jo + t);
                ns[t] = __shfl(nj, (q << 4) + jo + t);
            }
#pragma unroll
            for (int t = 0; t < 8; ++t)
                vs[t] = *(const float2*)(xin + cs[t] + (ql << 2));
#pragma unroll
            for (int t = 0; t < 8; ++t) {
                const __half2* hp = (const __half2*)&vs[t];
                float2 a = __half22float2(hp[0]);
                float2 b = __half22float2(hp[1]);
                ax += ns[t] * a.x;
                ay += ns[t] * a.y;
                az += ns[t] * b.x;
                aw += ns[t] * b.y;
            }
        }
    }
    float dr = dinv[node];
    union { float2 f2; __half2 h2[2]; } u;
    u.h2[0] = __floats2half2_rn(dr * ax, dr * ay);
    u.h2[1] = __floats2half2_rn(dr * az, dr * aw);
    *(float2*)(xout + base + (ql << 2)) = u.f2;
}

// combined weights Wc[j][ci][co], j in {x, Px, P2x, P3x}
__global__ void combine_w_kernel(const float* __restrict__ tf, const float* __restrict__ tb,
                                 float* __restrict__ wc) {
    int idx = blockIdx.x * blockDim.x + threadIdx.x;
    if (idx >= 4 * 64 * 64) return;
    int j = idx >> 12;
    int rem = idx & 4095;  // ci*64 + co
    float v;
    if (j == 0)      v = tf[rem];                         // Tf0
    else if (j == 1) v = tb[rem] + tb[4096 + rem];        // Tb0 + Tb1
    else if (j == 2) v = tf[4096 + rem] + tb[8192 + rem]; // Tf1 + Tb2
    else             v = tf[8192 + rem];                  // Tf2
    wc[idx] = v;
}

// out_tile = sum_j Xj_tile @ Wc[j]; Xj half -> fp32 LDS (transposed)
__global__ __launch_bounds__(256) void gemm4_kernel(
        const __half* __restrict__ x0, const __half* __restrict__ x1,
        const __half* __restrict__ x2, const __half* __restrict__ x3,
        const float* __restrict__ wc, float* __restrict__ out) {
    __shared__ float XsT[64][68];
    __shared__ float Ws[64][64];
    const int tid = threadIdx.x;
    const int tx = tid & 15;
    const int ty = tid >> 4;
    const int nb = blockIdx.x << 6;
    const __half* srcs[4] = {x0, x1, x2, x3};
    float acc[4][4];
#pragma unroll
    for (int i = 0; i < 4; ++i)
#pragma unroll
        for (int j = 0; j < 4; ++j) acc[i][j] = 0.f;

    for (int j = 0; j < 4; ++j) {
        const __half* src = srcs[j];
        const float4* wsrc = (const float4*)(wc + (j << 12));
#pragma unroll
        for (int it = 0; it < 4; ++it) {
            int f = tid + (it << 8);
            int r = f >> 4;
            int c4 = f & 15;
            float4 wv = wsrc[f];
            *(float4*)&Ws[r][c4 << 2] = wv;
            int n = nb + r;
            float2 a = make_float2(0.f, 0.f), b = make_float2(0.f, 0.f);
            if (n < N_NODES) {
                float2 raw = *(const float2*)(src + ((size_t)n << 6) + (c4 << 2));
                const __half2* hp = (const __half2*)&raw;
                a = __half22float2(hp[0]);
                b = __half22float2(hp[1]);
            }
            XsT[(c4 << 2) + 0][r] = a.x;
            XsT[(c4 << 2) + 1][r] = a.y;
            XsT[(c4 << 2) + 2][r] = b.x;
            XsT[(c4 << 2) + 3][r] = b.y;
        }
        __syncthreads();
#pragma unroll 8
        for (int k = 0; k < 64; ++k) {
            float4 bv = *(const float4*)&Ws[k][tx << 2];
            float4 av = *(const float4*)&XsT[k][ty << 2];
            acc[0][0] += av.x * bv.x; acc[0][1] += av.x * bv.y;
            acc[0][2] += av.x * bv.z; acc[0][3] += av.x * bv.w;
            acc[1][0] += av.y * bv.x; acc[1][1] += av.y * bv.y;
            acc[1][2] += av.y * bv.z; acc[1][3] += av.y * bv.w;
            acc[2][0] += av.z * bv.x; acc[2][1] += av.z * bv.y;
            acc[2][2] += av.z * bv.z; acc[2][3] += av.z * bv.w;
            acc[3][0] += av.w * bv.x; acc[3][1] += av.w * bv.y;
            acc[3][2] += av.w * bv.z; acc[3][3] += av.w * bv.w;
        }
        __syncthreads();
    }
#pragma unroll
    for (int i = 0; i < 4; ++i) {
        int n = nb + (ty << 2) + i;
        if (n < N_NODES) {
            float4 v = make_float4(acc[i][0], acc[i][1], acc[i][2], acc[i][3]);
            *(float4*)(out + ((size_t)n << 6) + (tx << 2)) = v;
        }
    }
}

extern "C" void kernel_launch(void* const* d_in, const int* in_sizes, int n_in,
                              void* d_out, int out_size, void* d_ws, size_t ws_size,
                              hipStream_t stream) {
    const float* x  = (const float*)d_in[0];
    const int*   ei = (const int*)d_in[1];   // row = ei[0..E), col = ei[E..2E)
    const float* ew = (const float*)d_in[2];
    const float* tf = (const float*)d_in[3];
    const float* tb = (const float*)d_in[4];
    float* out = (float*)d_out;

    const int* row = ei;
    const int* col = ei + N_EDGES;

    // workspace layout (4B words), total ~46 MB
    const int NROWS_PAD = NPART * 256;   // 50176
    float* ws = (float*)d_ws;
    size_t off = 0;
    int*    cntmat = (int*)(ws + off); off += NPART * NEB;       // 19208
    int*    offmat = (int*)(ws + off); off += NPART * NEB;
    uint2*  pedges = (uint2*)(ws + off); off += (size_t)N_EDGES * 2;
    unsigned int* bkt = (unsigned int*)(ws + off); off += (size_t)NROWS_PAD * CAP;
    int*    cnt  = (int*)(ws + off); off += NROWS_PAD;
    float*  dinv = ws + off; off += NROWS_PAD;
    __half* xh   = (__half*)(ws + off); off += (size_t)N_NODES * C / 2;
    __half* tA   = (__half*)(ws + off); off += (size_t)N_NODES * C / 2;
    __half* tB   = (__half*)(ws + off); off += (size_t)N_NODES * C / 2;
    __half* tC   = (__half*)(ws + off); off += (size_t)N_NODES * C / 2;
    float*  wc   = ws + off; off += 4 * 64 * 64;

    hist_kernel<<<NEB + XH_BLOCKS, 1024, 0, stream>>>(row, cntmat, x, xh);
    scan_kernel<<<1, 1024, 0, stream>>>(cntmat, offmat);
    scatter_kernel<<<NEB, 1024, 0, stream>>>(row, col, ew, offmat, pedges);
    build_kernel<<<NPART, 1024, 0, stream>>>(pedges, offmat, bkt, cnt, dinv);

    const int PB = (N_NODES + 15) / 16;   // 4 nodes/wave, 4 waves/block
    prop_kernel<<<PB, 256, 0, stream>>>(xh, tA, cnt, bkt, dinv);   // tx1
    prop_kernel<<<PB, 256, 0, stream>>>(tA, tB, cnt, bkt, dinv);   // tx2
    prop_kernel<<<PB, 256, 0, stream>>>(tB, tC, cnt, bkt, dinv);   // tx3

    combine_w_kernel<<<(4 * 64 * 64 + 255) / 256, 256, 0, stream>>>(tf, tb, wc);

    const int GB = (N_NODES + 63) / 64;
    gemm4_kernel<<<GB, 256, 0, stream>>>(xh, tA, tB, tC, wc, out);
}

// Round 10
// 200.875 us; speedup vs baseline: 1.1048x; 1.0779x over previous
//
#include <hip/hip_runtime.h>
#include <hip/hip_fp16.h>

// DiffusionConv: out = x@Tf0 + Px@(Tb0+Tb1) + P2x@(Tf1+Tb2) + P3x@Tf2
// R10: R9's single-block scan over cntmat[19208] re-created the R2
// anti-pattern (serialized global reads, ~35-45us). Two-level scan now:
// 76-block level-1, one-wave level-2, 76-block finalize. Rest = R9:
// hist(+xhalf) -> scan -> partition-scatter -> per-partition LDS binning,
// fp16 features, 3 gather props, one 4-term GEMM.

#define N_NODES 50000
#define N_EDGES 800000
#define C 64
#define CAP 64          // bucket capacity; rows ~ Poisson(16), P(>64) ~ 2e-18
#define NPART 196       // partitions of 256 rows: p = r >> 8
#define EPB 8192        // edges per block in hist/scatter
#define NEB 98          // ceil(800000/8192)
#define XH_BLOCKS 782   // ceil(800000 float4 chunks / 1024)
#define NTOT (NPART * NEB)            // 19208
#define S2NB ((NTOT + 255) / 256)     // 76

// A: blocks 0..NEB-1: partition histogram; blocks NEB..: x fp32->fp16
__global__ __launch_bounds__(1024) void hist_kernel(
        const int* __restrict__ row, int* __restrict__ cntmat,
        const float* __restrict__ x, __half* __restrict__ xh) {
    const int tid = threadIdx.x;
    if (blockIdx.x >= NEB) {
        int i = (blockIdx.x - NEB) * 1024 + tid;
        if (i < N_NODES * C / 4) {
            float4 v = ((const float4*)x)[i];
            union { float2 f2; __half2 h2[2]; } u;
            u.h2[0] = __floats2half2_rn(v.x, v.y);
            u.h2[1] = __floats2half2_rn(v.z, v.w);
            ((float2*)xh)[i] = u.f2;
        }
        return;
    }
    __shared__ int h[NPART];
    if (tid < NPART) h[tid] = 0;
    __syncthreads();
    int base = blockIdx.x * EPB;
#pragma unroll
    for (int i = 0; i < 8; ++i) {
        int e = base + i * 1024 + tid;
        if (e < N_EDGES) atomicAdd(&h[row[e] >> 8], 1);
    }
    __syncthreads();
    if (tid < NPART) cntmat[tid * NEB + blockIdx.x] = h[tid];
}

// B1: per-block inclusive scan of cntmat -> incl (in offmat), block sums
__global__ __launch_bounds__(256) void scan1_kernel(
        const int* __restrict__ cntmat, int* __restrict__ incl,
        int* __restrict__ sblk) {
    __shared__ int s[256];
    const int t = threadIdx.x;
    int i = blockIdx.x * 256 + t;
    int v = (i < NTOT) ? cntmat[i] : 0;
    s[t] = v;
    __syncthreads();
#pragma unroll
    for (int ofs = 1; ofs < 256; ofs <<= 1) {
        int u = (t >= ofs) ? s[t - ofs] : 0;
        __syncthreads();
        s[t] += u;
        __syncthreads();
    }
    if (i < NTOT) incl[i] = s[t];
    if (t == 255) sblk[blockIdx.x] = s[255];
}

// B2: one block scans sblk[S2NB] -> exclusive sblk_off
__global__ __launch_bounds__(128) void scan2_kernel(
        const int* __restrict__ sblk, int* __restrict__ sblk_off) {
    __shared__ int s[128];
    const int t = threadIdx.x;
    int v = (t < S2NB) ? sblk[t] : 0;
    s[t] = v;
    __syncthreads();
#pragma unroll
    for (int ofs = 1; ofs < 128; ofs <<= 1) {
        int u = (t >= ofs) ? s[t - ofs] : 0;
        __syncthreads();
        s[t] += u;
        __syncthreads();
    }
    if (t < S2NB) sblk_off[t] = s[t] - v;   // exclusive
}

// B3: offmat[i] = incl[i] - cntmat[i] + sblk_off[b]  (exclusive)
__global__ __launch_bounds__(256) void scan3_kernel(
        const int* __restrict__ cntmat, int* __restrict__ offmat,
        const int* __restrict__ sblk_off) {
    int i = blockIdx.x * 256 + threadIdx.x;
    if (i >= NTOT) return;
    offmat[i] = offmat[i] - cntmat[i] + sblk_off[blockIdx.x];
}

// C: partition-sorted scatter. Block b claims LDS cursors from offmat[.][b],
// writes uint2{col<<16|half(w), r&255} runs per partition (merged lines).
__global__ __launch_bounds__(1024) void scatter_kernel(
        const int* __restrict__ row, const int* __restrict__ col,
        const float* __restrict__ w, const int* __restrict__ offmat,
        uint2* __restrict__ pedges) {
    __shared__ int cur[NPART];
    const int tid = threadIdx.x;
    if (tid < NPART) cur[tid] = offmat[tid * NEB + blockIdx.x];
    __syncthreads();
    int base = blockIdx.x * EPB;
#pragma unroll
    for (int i = 0; i < 8; ++i) {
        int e = base + i * 1024 + tid;
        if (e < N_EDGES) {
            int r = row[e];
            unsigned int c = (unsigned int)col[e];
            unsigned int wh = (unsigned int)__half_as_ushort(__float2half_rn(w[e]));
            int slot = atomicAdd(&cur[r >> 8], 1);
            pedges[slot] = make_uint2((c << 16) | wh, (unsigned int)(r & 255));
        }
    }
}

// D: one block per partition: LDS-bin 256 rows x 64 slots, fuse dinv,
// dump buckets contiguously.
__global__ __launch_bounds__(1024) void build_kernel(
        const uint2* __restrict__ pedges, const int* __restrict__ offmat,
        unsigned int* __restrict__ bkt, int* __restrict__ cnt,
        float* __restrict__ dinv) {
    __shared__ unsigned int lbuck[256 * CAP];   // 64 KB
    __shared__ int lcnt[256];
    const int tid = threadIdx.x;
    const int p = blockIdx.x;
    if (tid < 256) lcnt[tid] = 0;
    __syncthreads();
    int s = offmat[p * NEB];
    int e = (p == NPART - 1) ? N_EDGES : offmat[(p + 1) * NEB];
    for (int i = s + tid; i < e; i += 1024) {
        uint2 en = pedges[i];
        int rl = (int)en.y;
        int slot = atomicAdd(&lcnt[rl], 1);
        if (slot < CAP) lbuck[(rl << 6) + slot] = en.x;
    }
    __syncthreads();
    if (tid < 256) {
        int m = min(lcnt[tid], CAP);
        int g = (p << 8) + tid;
        float sum = 0.f;
        for (int j = 0; j < m; ++j)
            sum += __half2float(__ushort_as_half(
                (unsigned short)(lbuck[(tid << 6) + j] & 0xFFFFu)));
        if (g < N_NODES) {
            cnt[g] = m;
            dinv[g] = (sum > 0.f) ? rsqrtf(sum) : 0.f;
        }
    }
    __syncthreads();
    // contiguous 64 KB dump (uint4-vectorized)
    const uint4* src = (const uint4*)lbuck;
    uint4* dst = (uint4*)(bkt + ((size_t)p << 14));
    for (int i = tid; i < 256 * CAP / 4; i += 1024) dst[i] = src[i];
}

// 4 nodes per wave: quarter-wave q owns node wave*4+q; lane ql (0-15) holds
// channels 4ql..4ql+3. 8B gathers; dinv[col] per edge; dinv[row] at epilogue.
__global__ __launch_bounds__(256) void prop_kernel(
        const __half* __restrict__ xin, __half* __restrict__ xout,
        const int* __restrict__ cnt, const unsigned int* __restrict__ bkt,
        const float* __restrict__ dinv) {
    int wave = (blockIdx.x * blockDim.x + threadIdx.x) >> 6;
    int lane = threadIdx.x & 63;
    int q = lane >> 4;
    int ql = lane & 15;
    int node = (wave << 2) + q;     // 12500 waves * 4 = 50000 exactly
    if (node >= N_NODES) return;
    int m = min(cnt[node], CAP);
    int base = node << 6;
    float ax = 0.f, ay = 0.f, az = 0.f, aw = 0.f;
    for (int cb = 0; cb < m; cb += 16) {
        int cj = 0;
        float nj = 0.f;
        int idx = cb + ql;
        if (idx < m) {
            unsigned int b = bkt[base + idx];
            int c = (int)(b >> 16);
            cj = c << 6;                                   // half-elem row offset
            nj = __half2float(__ushort_as_half((unsigned short)(b & 0xFFFFu))) * dinv[c];
        }
        int rem = m - cb;
        if (rem > 16) rem = 16;
        int mm = (rem + 7) & ~7;    // padded lanes carry cj=0,nj=0
        for (int jo = 0; jo < mm; jo += 8) {
            int cs[8];
            float ns[8];
            float2 vs[8];
#pragma unroll
            for (int t = 0; t < 8; ++t) {
                cs[t] = __shfl(cj, (q << 4) + jo + t);
                ns[t] = __shfl(nj, (q << 4) + jo + t);
            }
#pragma unroll
            for (int t = 0; t < 8; ++t)
                vs[t] = *(const float2*)(xin + cs[t] + (ql << 2));
#pragma unroll
            for (int t = 0; t < 8; ++t) {
                const __half2* hp = (const __half2*)&vs[t];
                float2 a = __half22float2(hp[0]);
                float2 b = __half22float2(hp[1]);
                ax += ns[t] * a.x;
                ay += ns[t] * a.y;
                az += ns[t] * b.x;
                aw += ns[t] * b.y;
            }
        }
    }
    float dr = dinv[node];
    union { float2 f2; __half2 h2[2]; } u;
    u.h2[0] = __floats2half2_rn(dr * ax, dr * ay);
    u.h2[1] = __floats2half2_rn(dr * az, dr * aw);
    *(float2*)(xout + base + (ql << 2)) = u.f2;
}

// combined weights Wc[j][ci][co], j in {x, Px, P2x, P3x}
__global__ void combine_w_kernel(const float* __restrict__ tf, const float* __restrict__ tb,
                                 float* __restrict__ wc) {
    int idx = blockIdx.x * blockDim.x + threadIdx.x;
    if (idx >= 4 * 64 * 64) return;
    int j = idx >> 12;
    int rem = idx & 4095;  // ci*64 + co
    float v;
    if (j == 0)      v = tf[rem];                         // Tf0
    else if (j == 1) v = tb[rem] + tb[4096 + rem];        // Tb0 + Tb1
    else if (j == 2) v = tf[4096 + rem] + tb[8192 + rem]; // Tf1 + Tb2
    else             v = tf[8192 + rem];                  // Tf2
    wc[idx] = v;
}

// out_tile = sum_j Xj_tile @ Wc[j]; Xj half -> fp32 LDS (transposed)
__global__ __launch_bounds__(256) void gemm4_kernel(
        const __half* __restrict__ x0, const __half* __restrict__ x1,
        const __half* __restrict__ x2, const __half* __restrict__ x3,
        const float* __restrict__ wc, float* __restrict__ out) {
    __shared__ float XsT[64][68];
    __shared__ float Ws[64][64];
    const int tid = threadIdx.x;
    const int tx = tid & 15;
    const int ty = tid >> 4;
    const int nb = blockIdx.x << 6;
    const __half* srcs[4] = {x0, x1, x2, x3};
    float acc[4][4];
#pragma unroll
    for (int i = 0; i < 4; ++i)
#pragma unroll
        for (int j = 0; j < 4; ++j) acc[i][j] = 0.f;

    for (int j = 0; j < 4; ++j) {
        const __half* src = srcs[j];
        const float4* wsrc = (const float4*)(wc + (j << 12));
#pragma unroll
        for (int it = 0; it < 4; ++it) {
            int f = tid + (it << 8);
            int r = f >> 4;
            int c4 = f & 15;
            float4 wv = wsrc[f];
            *(float4*)&Ws[r][c4 << 2] = wv;
            int n = nb + r;
            float2 a = make_float2(0.f, 0.f), b = make_float2(0.f, 0.f);
            if (n < N_NODES) {
                float2 raw = *(const float2*)(src + ((size_t)n << 6) + (c4 << 2));
                const __half2* hp = (const __half2*)&raw;
                a = __half22float2(hp[0]);
                b = __half22float2(hp[1]);
            }
            XsT[(c4 << 2) + 0][r] = a.x;
            XsT[(c4 << 2) + 1][r] = a.y;
            XsT[(c4 << 2) + 2][r] = b.x;
            XsT[(c4 << 2) + 3][r] = b.y;
        }
        __syncthreads();
#pragma unroll 8
        for (int k = 0; k < 64; ++k) {
            float4 bv = *(const float4*)&Ws[k][tx << 2];
            float4 av = *(const float4*)&XsT[k][ty << 2];
            acc[0][0] += av.x * bv.x; acc[0][1] += av.x * bv.y;
            acc[0][2] += av.x * bv.z; acc[0][3] += av.x * bv.w;
            acc[1][0] += av.y * bv.x; acc[1][1] += av.y * bv.y;
            acc[1][2] += av.y * bv.z; acc[1][3] += av.y * bv.w;
            acc[2][0] += av.z * bv.x; acc[2][1] += av.z * bv.y;
            acc[2][2] += av.z * bv.z; acc[2][3] += av.z * bv.w;
            acc[3][0] += av.w * bv.x; acc[3][1] += av.w * bv.y;
            acc[3][2] += av.w * bv.z; acc[3][3] += av.w * bv.w;
        }
        __syncthreads();
    }
#pragma unroll
    for (int i = 0; i < 4; ++i) {
        int n = nb + (ty << 2) + i;
        if (n < N_NODES) {
            float4 v = make_float4(acc[i][0], acc[i][1], acc[i][2], acc[i][3]);
            *(float4*)(out + ((size_t)n << 6) + (tx << 2)) = v;
        }
    }
}

extern "C" void kernel_launch(void* const* d_in, const int* in_sizes, int n_in,
                              void* d_out, int out_size, void* d_ws, size_t ws_size,
                              hipStream_t stream) {
    const float* x  = (const float*)d_in[0];
    const int*   ei = (const int*)d_in[1];   // row = ei[0..E), col = ei[E..2E)
    const float* ew = (const float*)d_in[2];
    const float* tf = (const float*)d_in[3];
    const float* tb = (const float*)d_in[4];
    float* out = (float*)d_out;

    const int* row = ei;
    const int* col = ei + N_EDGES;

    // workspace layout (4B words), total ~46 MB
    const int NROWS_PAD = NPART * 256;   // 50176
    float* ws = (float*)d_ws;
    size_t off = 0;
    int*    cntmat = (int*)(ws + off); off += NTOT;
    int*    offmat = (int*)(ws + off); off += NTOT;
    int*    sblk   = (int*)(ws + off); off += 128;
    int*    sblk_off = (int*)(ws + off); off += 128;
    uint2*  pedges = (uint2*)(ws + off); off += (size_t)N_EDGES * 2;
    unsigned int* bkt = (unsigned int*)(ws + off); off += (size_t)NROWS_PAD * CAP;
    int*    cnt  = (int*)(ws + off); off += NROWS_PAD;
    float*  dinv = ws + off; off += NROWS_PAD;
    __half* xh   = (__half*)(ws + off); off += (size_t)N_NODES * C / 2;
    __half* tA   = (__half*)(ws + off); off += (size_t)N_NODES * C / 2;
    __half* tB   = (__half*)(ws + off); off += (size_t)N_NODES * C / 2;
    __half* tC   = (__half*)(ws + off); off += (size_t)N_NODES * C / 2;
    float*  wc   = ws + off; off += 4 * 64 * 64;

    hist_kernel<<<NEB + XH_BLOCKS, 1024, 0, stream>>>(row, cntmat, x, xh);
    scan1_kernel<<<S2NB, 256, 0, stream>>>(cntmat, offmat, sblk);   // incl -> offmat
    scan2_kernel<<<1, 128, 0, stream>>>(sblk, sblk_off);
    scan3_kernel<<<S2NB, 256, 0, stream>>>(cntmat, offmat, sblk_off);
    scatter_kernel<<<NEB, 1024, 0, stream>>>(row, col, ew, offmat, pedges);
    build_kernel<<<NPART, 1024, 0, stream>>>(pedges, offmat, bkt, cnt, dinv);

    const int PB = (N_NODES + 15) / 16;   // 4 nodes/wave, 4 waves/block
    prop_kernel<<<PB, 256, 0, stream>>>(xh, tA, cnt, bkt, dinv);   // tx1
    prop_kernel<<<PB, 256, 0, stream>>>(tA, tB, cnt, bkt, dinv);   // tx2
    prop_kernel<<<PB, 256, 0, stream>>>(tB, tC, cnt, bkt, dinv);   // tx3

    combine_w_kernel<<<(4 * 64 * 64 + 255) / 256, 256, 0, stream>>>(tf, tb, wc);

    const int GB = (N_NODES + 63) / 64;
    gemm4_kernel<<<GB, 256, 0, stream>>>(xh, tA, tB, tC, wc, out);
}

// Round 11
// 182.594 us; speedup vs baseline: 1.2155x; 1.1001x over previous
//
#include <hip/hip_runtime.h>
#include <hip/hip_fp16.h>

// DiffusionConv: out = x@Tf0 + Px@(Tb0+Tb1) + P2x@(Tf1+Tb2) + P3x@Tf2
// R11: GEMM -> MFMA (v_mfma_f32_16x16x32_f16), no LDS: A-frags straight from
// fp16 feature rows, B-frags from fp16 TRANSPOSED combined weights
// whc[j][co][ci] (contiguous 16B per fragment). combine_w fused into hist.
// Rest = R10: hist(+xhalf) -> 2-level scan -> partition scatter ->
// per-partition LDS binning -> 3 gather props.

#define N_NODES 50000
#define N_EDGES 800000
#define C 64
#define CAP 64          // bucket capacity; rows ~ Poisson(16), P(>64) ~ 2e-18
#define NPART 196       // partitions of 256 rows: p = r >> 8
#define EPB 8192        // edges per block in hist/scatter
#define NEB 98          // ceil(800000/8192)
#define XH_BLOCKS 782   // ceil(800000 float4 chunks / 1024)
#define CW_BLOCKS 16    // 16384 weight elems / 1024
#define NTOT (NPART * NEB)            // 19208
#define S2NB ((NTOT + 255) / 256)     // 76

typedef _Float16 half8 __attribute__((ext_vector_type(8)));
typedef float f32x4 __attribute__((ext_vector_type(4)));

// A: blocks [0,NEB): partition histogram; [NEB,NEB+XH): x fp32->fp16;
//    [NEB+XH, NEB+XH+CW): combined weights -> fp16 transposed whc[j][co][ci]
__global__ __launch_bounds__(1024) void hist_kernel(
        const int* __restrict__ row, int* __restrict__ cntmat,
        const float* __restrict__ x, __half* __restrict__ xh,
        const float* __restrict__ tf, const float* __restrict__ tb,
        _Float16* __restrict__ whc) {
    const int tid = threadIdx.x;
    if (blockIdx.x >= NEB + XH_BLOCKS) {
        int idx = (blockIdx.x - NEB - XH_BLOCKS) * 1024 + tid;  // < 16384
        int j = idx >> 12;
        int rem = idx & 4095;   // ci*64 + co
        int ci = rem >> 6;
        int co = rem & 63;
        float v;
        if (j == 0)      v = tf[rem];                         // Tf0
        else if (j == 1) v = tb[rem] + tb[4096 + rem];        // Tb0 + Tb1
        else if (j == 2) v = tf[4096 + rem] + tb[8192 + rem]; // Tf1 + Tb2
        else             v = tf[8192 + rem];                  // Tf2
        whc[(j << 12) + (co << 6) + ci] = (_Float16)v;        // transposed
        return;
    }
    if (blockIdx.x >= NEB) {
        int i = (blockIdx.x - NEB) * 1024 + tid;
        if (i < N_NODES * C / 4) {
            float4 v = ((const float4*)x)[i];
            union { float2 f2; __half2 h2[2]; } u;
            u.h2[0] = __floats2half2_rn(v.x, v.y);
            u.h2[1] = __floats2half2_rn(v.z, v.w);
            ((float2*)xh)[i] = u.f2;
        }
        return;
    }
    __shared__ int h[NPART];
    if (tid < NPART) h[tid] = 0;
    __syncthreads();
    int base = blockIdx.x * EPB;
#pragma unroll
    for (int i = 0; i < 8; ++i) {
        int e = base + i * 1024 + tid;
        if (e < N_EDGES) atomicAdd(&h[row[e] >> 8], 1);
    }
    __syncthreads();
    if (tid < NPART) cntmat[tid * NEB + blockIdx.x] = h[tid];
}

// B1: per-block inclusive scan of cntmat -> incl (in offmat), block sums
__global__ __launch_bounds__(256) void scan1_kernel(
        const int* __restrict__ cntmat, int* __restrict__ incl,
        int* __restrict__ sblk) {
    __shared__ int s[256];
    const int t = threadIdx.x;
    int i = blockIdx.x * 256 + t;
    int v = (i < NTOT) ? cntmat[i] : 0;
    s[t] = v;
    __syncthreads();
#pragma unroll
    for (int ofs = 1; ofs < 256; ofs <<= 1) {
        int u = (t >= ofs) ? s[t - ofs] : 0;
        __syncthreads();
        s[t] += u;
        __syncthreads();
    }
    if (i < NTOT) incl[i] = s[t];
    if (t == 255) sblk[blockIdx.x] = s[255];
}

// B2: one block scans sblk[S2NB] -> exclusive sblk_off
__global__ __launch_bounds__(128) void scan2_kernel(
        const int* __restrict__ sblk, int* __restrict__ sblk_off) {
    __shared__ int s[128];
    const int t = threadIdx.x;
    int v = (t < S2NB) ? sblk[t] : 0;
    s[t] = v;
    __syncthreads();
#pragma unroll
    for (int ofs = 1; ofs < 128; ofs <<= 1) {
        int u = (t >= ofs) ? s[t - ofs] : 0;
        __syncthreads();
        s[t] += u;
        __syncthreads();
    }
    if (t < S2NB) sblk_off[t] = s[t] - v;   // exclusive
}

// B3: offmat[i] = incl[i] - cntmat[i] + sblk_off[b]  (exclusive)
__global__ __launch_bounds__(256) void scan3_kernel(
        const int* __restrict__ cntmat, int* __restrict__ offmat,
        const int* __restrict__ sblk_off) {
    int i = blockIdx.x * 256 + threadIdx.x;
    if (i >= NTOT) return;
    offmat[i] = offmat[i] - cntmat[i] + sblk_off[blockIdx.x];
}

// C: partition-sorted scatter. Block b claims LDS cursors from offmat[.][b],
// writes uint2{col<<16|half(w), r&255} runs per partition (merged lines).
__global__ __launch_bounds__(1024) void scatter_kernel(
        const int* __restrict__ row, const int* __restrict__ col,
        const float* __restrict__ w, const int* __restrict__ offmat,
        uint2* __restrict__ pedges) {
    __shared__ int cur[NPART];
    const int tid = threadIdx.x;
    if (tid < NPART) cur[tid] = offmat[tid * NEB + blockIdx.x];
    __syncthreads();
    int base = blockIdx.x * EPB;
#pragma unroll
    for (int i = 0; i < 8; ++i) {
        int e = base + i * 1024 + tid;
        if (e < N_EDGES) {
            int r = row[e];
            unsigned int c = (unsigned int)col[e];
            unsigned int wh = (unsigned int)__half_as_ushort(__float2half_rn(w[e]));
            int slot = atomicAdd(&cur[r >> 8], 1);
            pedges[slot] = make_uint2((c << 16) | wh, (unsigned int)(r & 255));
        }
    }
}

// D: one block per partition: LDS-bin 256 rows x 64 slots, fuse dinv,
// dump buckets contiguously.
__global__ __launch_bounds__(1024) void build_kernel(
        const uint2* __restrict__ pedges, const int* __restrict__ offmat,
        unsigned int* __restrict__ bkt, int* __restrict__ cnt,
        float* __restrict__ dinv) {
    __shared__ unsigned int lbuck[256 * CAP];   // 64 KB
    __shared__ int lcnt[256];
    const int tid = threadIdx.x;
    const int p = blockIdx.x;
    if (tid < 256) lcnt[tid] = 0;
    __syncthreads();
    int s = offmat[p * NEB];
    int e = (p == NPART - 1) ? N_EDGES : offmat[(p + 1) * NEB];
    for (int i = s + tid; i < e; i += 1024) {
        uint2 en = pedges[i];
        int rl = (int)en.y;
        int slot = atomicAdd(&lcnt[rl], 1);
        if (slot < CAP) lbuck[(rl << 6) + slot] = en.x;
    }
    __syncthreads();
    if (tid < 256) {
        int m = min(lcnt[tid], CAP);
        int g = (p << 8) + tid;
        float sum = 0.f;
        for (int j = 0; j < m; ++j)
            sum += __half2float(__ushort_as_half(
                (unsigned short)(lbuck[(tid << 6) + j] & 0xFFFFu)));
        if (g < N_NODES) {
            cnt[g] = m;
            dinv[g] = (sum > 0.f) ? rsqrtf(sum) : 0.f;
        }
    }
    __syncthreads();
    // contiguous 64 KB dump (uint4-vectorized)
    const uint4* src = (const uint4*)lbuck;
    uint4* dst = (uint4*)(bkt + ((size_t)p << 14));
    for (int i = tid; i < 256 * CAP / 4; i += 1024) dst[i] = src[i];
}

// 4 nodes per wave: quarter-wave q owns node wave*4+q; lane ql (0-15) holds
// channels 4ql..4ql+3. 8B gathers; dinv[col] per edge; dinv[row] at epilogue.
__global__ __launch_bounds__(256) void prop_kernel(
        const __half* __restrict__ xin, __half* __restrict__ xout,
        const int* __restrict__ cnt, const unsigned int* __restrict__ bkt,
        const float* __restrict__ dinv) {
    int wave = (blockIdx.x * blockDim.x + threadIdx.x) >> 6;
    int lane = threadIdx.x & 63;
    int q = lane >> 4;
    int ql = lane & 15;
    int node = (wave << 2) + q;     // 12500 waves * 4 = 50000 exactly
    if (node >= N_NODES) return;
    int m = min(cnt[node], CAP);
    int base = node << 6;
    float ax = 0.f, ay = 0.f, az = 0.f, aw = 0.f;
    for (int cb = 0; cb < m; cb += 16) {
        int cj = 0;
        float nj = 0.f;
        int idx = cb + ql;
        if (idx < m) {
            unsigned int b = bkt[base + idx];
            int c = (int)(b >> 16);
            cj = c << 6;                                   // half-elem row offset
            nj = __half2float(__ushort_as_half((unsigned short)(b & 0xFFFFu))) * dinv[c];
        }
        int rem = m - cb;
        if (rem > 16) rem = 16;
        int mm = (rem + 7) & ~7;    // padded lanes carry cj=0,nj=0
        for (int jo = 0; jo < mm; jo += 8) {
            int cs[8];
            float ns[8];
            float2 vs[8];
#pragma unroll
            for (int t = 0; t < 8; ++t) {
                cs[t] = __shfl(cj, (q << 4) + jo + t);
                ns[t] = __shfl(nj, (q << 4) + jo + t);
            }
#pragma unroll
            for (int t = 0; t < 8; ++t)
                vs[t] = *(const float2*)(xin + cs[t] + (ql << 2));
#pragma unroll
            for (int t = 0; t < 8; ++t) {
                const __half2* hp = (const __half2*)&vs[t];
                float2 a = __half22float2(hp[0]);
                float2 b = __half22float2(hp[1]);
                ax += ns[t] * a.x;
                ay += ns[t] * a.y;
                az += ns[t] * b.x;
                aw += ns[t] * b.y;
            }
        }
    }
    float dr = dinv[node];
    union { float2 f2; __half2 h2[2]; } u;
    u.h2[0] = __floats2half2_rn(dr * ax, dr * ay);
    u.h2[1] = __floats2half2_rn(dr * az, dr * aw);
    *(float2*)(xout + base + (ql << 2)) = u.f2;
}

// MFMA GEMM: out[r][co] = sum_j Xj[r][:] @ Wc[j][:][co], K=4*64.
// Wave owns 16 rows; 4 accumulator tiles (16x16) cover co 0..63.
// A-frag: A[m=lane&15][k=quad*8+i] -> 16B from xh row.
// B-frag: B[k=quad*8+i][n=lane&15] -> 16B from whc[j][n][k..] (transposed W).
// C/D: col=lane&15, row=quad*4+reg.
__global__ __launch_bounds__(256) void gemm_mfma_kernel(
        const __half* __restrict__ x0, const __half* __restrict__ x1,
        const __half* __restrict__ x2, const __half* __restrict__ x3,
        const _Float16* __restrict__ whc, float* __restrict__ out) {
    const int tid = threadIdx.x;
    const int wv = tid >> 6;
    const int lane = tid & 63;
    const int quad = lane >> 4;
    const int l16 = lane & 15;
    const int mbase = (blockIdx.x << 6) + (wv << 4);
    const __half* srcs[4] = {x0, x1, x2, x3};
    f32x4 acc0 = {}, acc1 = {}, acc2 = {}, acc3 = {};
    const int arow = mbase + l16;
    const bool aok = arow < N_NODES;
    const size_t abase = ((size_t)arow << 6) + (quad << 3);
    const half8 zero8 = {};
#pragma unroll
    for (int j = 0; j < 4; ++j) {
        const __half* src = srcs[j];
#pragma unroll
        for (int kk = 0; kk < 64; kk += 32) {
            half8 af = aok ? *(const half8*)(const void*)(src + abase + kk) : zero8;
            const _Float16* wb = whc + (j << 12) + kk + (quad << 3);
            half8 b0 = *(const half8*)(const void*)(wb + ((0 * 16 + l16) << 6));
            half8 b1 = *(const half8*)(const void*)(wb + ((1 * 16 + l16) << 6));
            half8 b2 = *(const half8*)(const void*)(wb + ((2 * 16 + l16) << 6));
            half8 b3 = *(const half8*)(const void*)(wb + ((3 * 16 + l16) << 6));
            acc0 = __builtin_amdgcn_mfma_f32_16x16x32_f16(af, b0, acc0, 0, 0, 0);
            acc1 = __builtin_amdgcn_mfma_f32_16x16x32_f16(af, b1, acc1, 0, 0, 0);
            acc2 = __builtin_amdgcn_mfma_f32_16x16x32_f16(af, b2, acc2, 0, 0, 0);
            acc3 = __builtin_amdgcn_mfma_f32_16x16x32_f16(af, b3, acc3, 0, 0, 0);
        }
    }
#pragma unroll
    for (int i = 0; i < 4; ++i) {
        int r = mbase + (quad << 2) + i;
        if (r < N_NODES) {
            float* dst = out + ((size_t)r << 6) + l16;
            dst[0]  = acc0[i];
            dst[16] = acc1[i];
            dst[32] = acc2[i];
            dst[48] = acc3[i];
        }
    }
}

extern "C" void kernel_launch(void* const* d_in, const int* in_sizes, int n_in,
                              void* d_out, int out_size, void* d_ws, size_t ws_size,
                              hipStream_t stream) {
    const float* x  = (const float*)d_in[0];
    const int*   ei = (const int*)d_in[1];   // row = ei[0..E), col = ei[E..2E)
    const float* ew = (const float*)d_in[2];
    const float* tf = (const float*)d_in[3];
    const float* tb = (const float*)d_in[4];
    float* out = (float*)d_out;

    const int* row = ei;
    const int* col = ei + N_EDGES;

    // workspace layout (4B words), total ~46 MB
    const int NROWS_PAD = NPART * 256;   // 50176
    float* ws = (float*)d_ws;
    size_t off = 0;
    int*    cntmat = (int*)(ws + off); off += NTOT;
    int*    offmat = (int*)(ws + off); off += NTOT + 48;  // pad to keep 16B align
    int*    sblk   = (int*)(ws + off); off += 128;
    int*    sblk_off = (int*)(ws + off); off += 128;
    uint2*  pedges = (uint2*)(ws + off); off += (size_t)N_EDGES * 2;
    unsigned int* bkt = (unsigned int*)(ws + off); off += (size_t)NROWS_PAD * CAP;
    int*    cnt  = (int*)(ws + off); off += NROWS_PAD;
    float*  dinv = ws + off; off += NROWS_PAD;
    __half* xh   = (__half*)(ws + off); off += (size_t)N_NODES * C / 2;
    __half* tA   = (__half*)(ws + off); off += (size_t)N_NODES * C / 2;
    __half* tB   = (__half*)(ws + off); off += (size_t)N_NODES * C / 2;
    __half* tC   = (__half*)(ws + off); off += (size_t)N_NODES * C / 2;
    _Float16* whc = (_Float16*)(ws + off); off += 4 * 64 * 64 / 2;

    hist_kernel<<<NEB + XH_BLOCKS + CW_BLOCKS, 1024, 0, stream>>>(
        row, cntmat, x, xh, tf, tb, whc);
    scan1_kernel<<<S2NB, 256, 0, stream>>>(cntmat, offmat, sblk);   // incl -> offmat
    scan2_kernel<<<1, 128, 0, stream>>>(sblk, sblk_off);
    scan3_kernel<<<S2NB, 256, 0, stream>>>(cntmat, offmat, sblk_off);
    scatter_kernel<<<NEB, 1024, 0, stream>>>(row, col, ew, offmat, pedges);
    build_kernel<<<NPART, 1024, 0, stream>>>(pedges, offmat, bkt, cnt, dinv);

    const int PB = (N_NODES + 15) / 16;   // 4 nodes/wave, 4 waves/block
    prop_kernel<<<PB, 256, 0, stream>>>(xh, tA, cnt, bkt, dinv);   // tx1
    prop_kernel<<<PB, 256, 0, stream>>>(tA, tB, cnt, bkt, dinv);   // tx2
    prop_kernel<<<PB, 256, 0, stream>>>(tB, tC, cnt, bkt, dinv);   // tx3

    const int GB = (N_NODES + 63) / 64;
    gemm_mfma_kernel<<<GB, 256, 0, stream>>>(xh, tA, tB, tC, whc, out);
}

// Round 12
// 165.893 us; speedup vs baseline: 1.3378x; 1.1007x over previous
//
#include <hip/hip_runtime.h>
#include <hip/hip_fp16.h>

// DiffusionConv: out = x@Tf0 + Px@(Tb0+Tb1) + P2x@(Tf1+Tb2) + P3x@Tf2
// R12: binning collapsed to ONE kernel. Partitions get fixed-capacity
// preallocated pedges regions (CAPP=4608 >= Poisson(4096)+8sigma); each
// block LDS-histograms its 8192 edges, atomically reserves chunks in
// percur[196] (19208 global atomics total), scatters from REGISTERS via
// LDS cursors. Replaces hist+scan1+scan2+scan3+scatter (5 launches -> 1).
// xh/whc converts ride in the same grid. Rest = R11: per-partition LDS
// build, 3 gather props, MFMA gemm.

#define N_NODES 50000
#define N_EDGES 800000
#define C 64
#define CAP 64          // bucket capacity; rows ~ Poisson(16), P(>64) ~ 2e-18
#define NPART 196       // partitions of 256 rows: p = r >> 8
#define CAPP 4608       // edges per partition region; mean 4096, +8 sigma
#define EPB 8192        // edges per block in scatter2
#define NEB 98          // ceil(800000/8192)
#define XH_BLOCKS 782   // ceil(800000 float4 chunks / 1024)
#define CW_BLOCKS 16    // 16384 weight elems / 1024

typedef _Float16 half8 __attribute__((ext_vector_type(8)));
typedef float f32x4 __attribute__((ext_vector_type(4)));

// Fused: blocks [0,NEB): hist+reserve+scatter; [NEB,NEB+XH): x fp32->fp16;
// [NEB+XH,..): combined weights -> fp16 transposed whc[j][co][ci]
__global__ __launch_bounds__(1024) void scatter2_kernel(
        const int* __restrict__ row, const int* __restrict__ col,
        const float* __restrict__ w, int* __restrict__ percur,
        uint2* __restrict__ pedges,
        const float* __restrict__ x, __half* __restrict__ xh,
        const float* __restrict__ tf, const float* __restrict__ tb,
        _Float16* __restrict__ whc) {
    const int tid = threadIdx.x;
    if (blockIdx.x >= NEB + XH_BLOCKS) {
        int idx = (blockIdx.x - NEB - XH_BLOCKS) * 1024 + tid;  // < 16384
        int j = idx >> 12;
        int rem = idx & 4095;   // ci*64 + co
        int ci = rem >> 6;
        int co = rem & 63;
        float v;
        if (j == 0)      v = tf[rem];                         // Tf0
        else if (j == 1) v = tb[rem] + tb[4096 + rem];        // Tb0 + Tb1
        else if (j == 2) v = tf[4096 + rem] + tb[8192 + rem]; // Tf1 + Tb2
        else             v = tf[8192 + rem];                  // Tf2
        whc[(j << 12) + (co << 6) + ci] = (_Float16)v;        // transposed
        return;
    }
    if (blockIdx.x >= NEB) {
        int i = (blockIdx.x - NEB) * 1024 + tid;
        if (i < N_NODES * C / 4) {
            float4 v = ((const float4*)x)[i];
            union { float2 f2; __half2 h2[2]; } u;
            u.h2[0] = __floats2half2_rn(v.x, v.y);
            u.h2[1] = __floats2half2_rn(v.z, v.w);
            ((float2*)xh)[i] = u.f2;
        }
        return;
    }
    __shared__ int h[NPART];
    __shared__ int cur[NPART];
    uint2 ent[8];
    int pp[8];
    if (tid < NPART) h[tid] = 0;
    __syncthreads();
    int base = blockIdx.x * EPB;
#pragma unroll
    for (int i = 0; i < 8; ++i) {
        int e = base + i * 1024 + tid;
        pp[i] = -1;
        if (e < N_EDGES) {
            int r = row[e];
            unsigned int c = (unsigned int)col[e];
            unsigned int wh = (unsigned int)__half_as_ushort(__float2half_rn(w[e]));
            ent[i] = make_uint2((c << 16) | wh, (unsigned int)(r & 255));
            pp[i] = r >> 8;
            atomicAdd(&h[pp[i]], 1);
        }
    }
    __syncthreads();
    if (tid < NPART) cur[tid] = atomicAdd(&percur[tid], h[tid]);
    __syncthreads();
#pragma unroll
    for (int i = 0; i < 8; ++i) {
        if (pp[i] >= 0) {
            int slot = atomicAdd(&cur[pp[i]], 1);
            pedges[(size_t)pp[i] * CAPP + slot] = ent[i];
        }
    }
}

// One block per partition: LDS-bin 256 rows x 64 slots, fuse dinv,
// dump buckets contiguously.
__global__ __launch_bounds__(1024) void build_kernel(
        const uint2* __restrict__ pedges, const int* __restrict__ percur,
        unsigned int* __restrict__ bkt, int* __restrict__ cnt,
        float* __restrict__ dinv) {
    __shared__ unsigned int lbuck[256 * CAP];   // 64 KB
    __shared__ int lcnt[256];
    const int tid = threadIdx.x;
    const int p = blockIdx.x;
    if (tid < 256) lcnt[tid] = 0;
    __syncthreads();
    int e = min(percur[p], CAPP);
    const uint2* src = pedges + (size_t)p * CAPP;
    for (int i = tid; i < e; i += 1024) {
        uint2 en = src[i];
        int rl = (int)en.y;
        int slot = atomicAdd(&lcnt[rl], 1);
        if (slot < CAP) lbuck[(rl << 6) + slot] = en.x;
    }
    __syncthreads();
    if (tid < 256) {
        int m = min(lcnt[tid], CAP);
        int g = (p << 8) + tid;
        float sum = 0.f;
        for (int j = 0; j < m; ++j)
            sum += __half2float(__ushort_as_half(
                (unsigned short)(lbuck[(tid << 6) + j] & 0xFFFFu)));
        if (g < N_NODES) {
            cnt[g] = m;
            dinv[g] = (sum > 0.f) ? rsqrtf(sum) : 0.f;
        }
    }
    __syncthreads();
    // contiguous 64 KB dump (uint4-vectorized)
    const uint4* s4 = (const uint4*)lbuck;
    uint4* dst = (uint4*)(bkt + ((size_t)p << 14));
    for (int i = tid; i < 256 * CAP / 4; i += 1024) dst[i] = s4[i];
}

// 4 nodes per wave: quarter-wave q owns node wave*4+q; lane ql (0-15) holds
// channels 4ql..4ql+3. 8B gathers; dinv[col] per edge; dinv[row] at epilogue.
__global__ __launch_bounds__(256) void prop_kernel(
        const __half* __restrict__ xin, __half* __restrict__ xout,
        const int* __restrict__ cnt, const unsigned int* __restrict__ bkt,
        const float* __restrict__ dinv) {
    int wave = (blockIdx.x * blockDim.x + threadIdx.x) >> 6;
    int lane = threadIdx.x & 63;
    int q = lane >> 4;
    int ql = lane & 15;
    int node = (wave << 2) + q;     // 12500 waves * 4 = 50000 exactly
    if (node >= N_NODES) return;
    int m = min(cnt[node], CAP);
    int base = node << 6;
    float ax = 0.f, ay = 0.f, az = 0.f, aw = 0.f;
    for (int cb = 0; cb < m; cb += 16) {
        int cj = 0;
        float nj = 0.f;
        int idx = cb + ql;
        if (idx < m) {
            unsigned int b = bkt[base + idx];
            int c = (int)(b >> 16);
            cj = c << 6;                                   // half-elem row offset
            nj = __half2float(__ushort_as_half((unsigned short)(b & 0xFFFFu))) * dinv[c];
        }
        int rem = m - cb;
        if (rem > 16) rem = 16;
        int mm = (rem + 7) & ~7;    // padded lanes carry cj=0,nj=0
        for (int jo = 0; jo < mm; jo += 8) {
            int cs[8];
            float ns[8];
            float2 vs[8];
#pragma unroll
            for (int t = 0; t < 8; ++t) {
                cs[t] = __shfl(cj, (q << 4) + jo + t);
                ns[t] = __shfl(nj, (q << 4) + jo + t);
            }
#pragma unroll
            for (int t = 0; t < 8; ++t)
                vs[t] = *(const float2*)(xin + cs[t] + (ql << 2));
#pragma unroll
            for (int t = 0; t < 8; ++t) {
                const __half2* hp = (const __half2*)&vs[t];
                float2 a = __half22float2(hp[0]);
                float2 b = __half22float2(hp[1]);
                ax += ns[t] * a.x;
                ay += ns[t] * a.y;
                az += ns[t] * b.x;
                aw += ns[t] * b.y;
            }
        }
    }
    float dr = dinv[node];
    union { float2 f2; __half2 h2[2]; } u;
    u.h2[0] = __floats2half2_rn(dr * ax, dr * ay);
    u.h2[1] = __floats2half2_rn(dr * az, dr * aw);
    *(float2*)(xout + base + (ql << 2)) = u.f2;
}

// MFMA GEMM: out[r][co] = sum_j Xj[r][:] @ Wc[j][:][co], K=4*64.
// A-frag: A[m=lane&15][k=quad*8+i] from xh row (16B).
// B-frag: B[k=quad*8+i][n=lane&15] from whc[j][n][k..] (transposed, 16B).
// C/D: col=lane&15, row=quad*4+reg.
__global__ __launch_bounds__(256) void gemm_mfma_kernel(
        const __half* __restrict__ x0, const __half* __restrict__ x1,
        const __half* __restrict__ x2, const __half* __restrict__ x3,
        const _Float16* __restrict__ whc, float* __restrict__ out) {
    const int tid = threadIdx.x;
    const int wv = tid >> 6;
    const int lane = tid & 63;
    const int quad = lane >> 4;
    const int l16 = lane & 15;
    const int mbase = (blockIdx.x << 6) + (wv << 4);
    const __half* srcs[4] = {x0, x1, x2, x3};
    f32x4 acc0 = {}, acc1 = {}, acc2 = {}, acc3 = {};
    const int arow = mbase + l16;
    const bool aok = arow < N_NODES;
    const size_t abase = ((size_t)arow << 6) + (quad << 3);
    const half8 zero8 = {};
#pragma unroll
    for (int j = 0; j < 4; ++j) {
        const __half* src = srcs[j];
#pragma unroll
        for (int kk = 0; kk < 64; kk += 32) {
            half8 af = aok ? *(const half8*)(const void*)(src + abase + kk) : zero8;
            const _Float16* wb = whc + (j << 12) + kk + (quad << 3);
            half8 b0 = *(const half8*)(const void*)(wb + ((0 * 16 + l16) << 6));
            half8 b1 = *(const half8*)(const void*)(wb + ((1 * 16 + l16) << 6));
            half8 b2 = *(const half8*)(const void*)(wb + ((2 * 16 + l16) << 6));
            half8 b3 = *(const half8*)(const void*)(wb + ((3 * 16 + l16) << 6));
            acc0 = __builtin_amdgcn_mfma_f32_16x16x32_f16(af, b0, acc0, 0, 0, 0);
            acc1 = __builtin_amdgcn_mfma_f32_16x16x32_f16(af, b1, acc1, 0, 0, 0);
            acc2 = __builtin_amdgcn_mfma_f32_16x16x32_f16(af, b2, acc2, 0, 0, 0);
            acc3 = __builtin_amdgcn_mfma_f32_16x16x32_f16(af, b3, acc3, 0, 0, 0);
        }
    }
#pragma unroll
    for (int i = 0; i < 4; ++i) {
        int r = mbase + (quad << 2) + i;
        if (r < N_NODES) {
            float* dst = out + ((size_t)r << 6) + l16;
            dst[0]  = acc0[i];
            dst[16] = acc1[i];
            dst[32] = acc2[i];
            dst[48] = acc3[i];
        }
    }
}

extern "C" void kernel_launch(void* const* d_in, const int* in_sizes, int n_in,
                              void* d_out, int out_size, void* d_ws, size_t ws_size,
                              hipStream_t stream) {
    const float* x  = (const float*)d_in[0];
    const int*   ei = (const int*)d_in[1];   // row = ei[0..E), col = ei[E..2E)
    const float* ew = (const float*)d_in[2];
    const float* tf = (const float*)d_in[3];
    const float* tb = (const float*)d_in[4];
    float* out = (float*)d_out;

    const int* row = ei;
    const int* col = ei + N_EDGES;

    // workspace layout (4B words), total ~46 MB
    const int NROWS_PAD = NPART * 256;   // 50176
    float* ws = (float*)d_ws;
    size_t off = 0;
    int*    percur = (int*)(ws + off); off += 256;
    uint2*  pedges = (uint2*)(ws + off); off += (size_t)NPART * CAPP * 2;
    unsigned int* bkt = (unsigned int*)(ws + off); off += (size_t)NROWS_PAD * CAP;
    int*    cnt  = (int*)(ws + off); off += NROWS_PAD;
    float*  dinv = ws + off; off += NROWS_PAD;
    __half* xh   = (__half*)(ws + off); off += (size_t)N_NODES * C / 2;
    __half* tA   = (__half*)(ws + off); off += (size_t)N_NODES * C / 2;
    __half* tB   = (__half*)(ws + off); off += (size_t)N_NODES * C / 2;
    __half* tC   = (__half*)(ws + off); off += (size_t)N_NODES * C / 2;
    _Float16* whc = (_Float16*)(ws + off); off += 4 * 64 * 64 / 2;

    hipMemsetAsync(percur, 0, NPART * sizeof(int), stream);

    scatter2_kernel<<<NEB + XH_BLOCKS + CW_BLOCKS, 1024, 0, stream>>>(
        row, col, ew, percur, pedges, x, xh, tf, tb, whc);
    build_kernel<<<NPART, 1024, 0, stream>>>(pedges, percur, bkt, cnt, dinv);

    const int PB = (N_NODES + 15) / 16;   // 4 nodes/wave, 4 waves/block
    prop_kernel<<<PB, 256, 0, stream>>>(xh, tA, cnt, bkt, dinv);   // tx1
    prop_kernel<<<PB, 256, 0, stream>>>(tA, tB, cnt, bkt, dinv);   // tx2
    prop_kernel<<<PB, 256, 0, stream>>>(tB, tC, cnt, bkt, dinv);   // tx3

    const int GB = (N_NODES + 63) / 64;
    gemm_mfma_kernel<<<GB, 256, 0, stream>>>(xh, tA, tB, tC, whc, out);
}